// Round 6
// baseline (5068.566 us; speedup 1.0000x reference)
//
#include <hip/hip_runtime.h>
#include <hip/hip_bf16.h>

// ---------------------------------------------------------------------------
// WinEncoderTransformer mega-kernel: one block per batch element (bc),
// activations resident in LDS (bf16), weights pre-transposed to bf16 in d_ws.
// Geometry: N=128, B=1024, C=256; block bc owns flat rows [bc*128, bc*128+128).
// R5 fix: scratch elimination. VGPR_Count pinned at 128 across all occupancy
// hints while WRITE_SIZE showed ~1.5MB/block scratch => the per-thread float
// arrays (ln v[64], lofi q/sc/o[32]) overflow the 128-arch-reg budget and live
// in scratch, thrashing L2 (weights re-fetched from HBM). Every phase is now
// restructured to fit ~100 arch regs: two-pass LN (live ~20), two-pass lofi
// softmax (live <=70), FFN halves (acc 64), qkv 48-col passes (acc 48).
// Also: barrier before the los write (it overlaps kvs rows>=64 — latent race).
// ---------------------------------------------------------------------------

#define ATT_SCALE 0.17677669529663687f   // 32^-0.5

typedef float f32x4 __attribute__((ext_vector_type(4)));
typedef __bf16 bf16x8 __attribute__((ext_vector_type(8)));
typedef unsigned short u16x8 __attribute__((ext_vector_type(8)));
typedef unsigned short u16x4 __attribute__((ext_vector_type(4)));

__device__ __forceinline__ unsigned short f2bf(float f) {
    unsigned int u = __float_as_uint(f);
    return (unsigned short)((u + 0x7FFFu + ((u >> 16) & 1u)) >> 16);  // RNE
}
__device__ __forceinline__ float bf2f(unsigned short s) {
    return __uint_as_float(((unsigned int)s) << 16);
}

// ---------------------------------------------------------------------------
// weight prep: src [L][K][N] f32 -> dst [L][N][K] bf16 (transposed)
// ---------------------------------------------------------------------------
__global__ __launch_bounds__(256) void wprep(const float* __restrict__ src,
                                             unsigned short* __restrict__ dst,
                                             int K, int N)
{
    __shared__ unsigned short t[32][33];
    int l = blockIdx.z;
    const float* s = src + (size_t)l * K * N;
    unsigned short* d = dst + (size_t)l * K * N;
    int r = threadIdx.x >> 3, c4 = (threadIdx.x & 7) * 4;
    int kb = blockIdx.x * 32, nb = blockIdx.y * 32;
    f32x4 v = *(const f32x4*)(s + (size_t)(kb + r) * N + nb + c4);
    #pragma unroll
    for (int j = 0; j < 4; ++j) t[c4 + j][r] = f2bf(v[j]);
    __syncthreads();
    u16x4 o;
    #pragma unroll
    for (int j = 0; j < 4; ++j) o[j] = t[r][c4 + j];
    *(u16x4*)(d + (size_t)(nb + r) * K + kb + c4) = o;
}

// ---------------------------------------------------------------------------
// MFMA tile GEMM: A from swizzled LDS (bf16), B from global transposed bf16.
// LDS swizzle convention everywhere: byte = (row*stride + colbyte) ^ ((row&7)<<4)
// ---------------------------------------------------------------------------
template<int MT, int NT, int KS>
__device__ __forceinline__ void mfma_gemm(const char* As, int astride, int am0,
    const unsigned short* __restrict__ BT, int ldbk, int koff,
    int lr, int lk, f32x4 (&acc)[MT][NT])
{
    #pragma unroll
    for (int s = 0; s < KS; ++s) {
        bf16x8 bfr[NT];
        #pragma unroll
        for (int nt = 0; nt < NT; ++nt)
            bfr[nt] = *(const bf16x8*)(BT + (size_t)(nt * 16 + lr) * ldbk + koff + s * 32 + lk * 8);
        #pragma unroll
        for (int mt = 0; mt < MT; ++mt) {
            int row = am0 + mt * 16 + lr;
            bf16x8 afr = *(const bf16x8*)(As + ((row * astride + s * 64 + lk * 16) ^ ((row & 7) << 4)));
            #pragma unroll
            for (int nt = 0; nt < NT; ++nt)
                acc[mt][nt] = __builtin_amdgcn_mfma_f32_16x16x32_bf16(afr, bfr[nt], acc[mt][nt], 0, 0, 0);
        }
    }
}

template<int MT, int NT, bool RELU>
__device__ __forceinline__ void store_lds(char* Ds, int dstride, int dm0, int dn0,
    const float* bias, int lr, int lk, f32x4 (&acc)[MT][NT])
{
    #pragma unroll
    for (int nt = 0; nt < NT; ++nt) {
        float bv = bias ? bias[nt * 16 + lr] : 0.0f;
        #pragma unroll
        for (int mt = 0; mt < MT; ++mt) {
            #pragma unroll
            for (int j = 0; j < 4; ++j) {
                int row = dm0 + mt * 16 + lk * 4 + j;
                int col = dn0 + nt * 16 + lr;
                float v = acc[mt][nt][j] + bv;
                if (RELU) v = fmaxf(v, 0.0f);
                *(unsigned short*)(Ds + ((row * dstride + col * 2) ^ ((row & 7) << 4))) = f2bf(v);
            }
        }
    }
}

// read 32 consecutive bf16 (4 swizzled 16B chunks) as floats
__device__ __forceinline__ void lds_read32(const char* base, int stride, int row, int cb, float* o) {
    int x = row * stride, sw = (row & 7) << 4;
    #pragma unroll
    for (int c = 0; c < 4; ++c) {
        u16x8 t = *(const u16x8*)(base + ((x + cb + c * 16) ^ sw));
        #pragma unroll
        for (int j = 0; j < 8; ++j) o[c * 8 + j] = bf2f(t[j]);
    }
}
__device__ __forceinline__ void lds_write32(char* base, int stride, int row, int cb, const float* v) {
    int x = row * stride, sw = (row & 7) << 4;
    #pragma unroll
    for (int c = 0; c < 4; ++c) {
        u16x8 t;
        #pragma unroll
        for (int j = 0; j < 8; ++j) t[j] = f2bf(v[c * 8 + j]);
        *(u16x8*)(base + ((x + cb + c * 16) ^ sw)) = t;
    }
}
// fused dot: sum_i q[i] * lds_row[i] over 32 bf16 (8-elem transient)
__device__ __forceinline__ float lds_dot32(const char* base, int stride, int row, int cb, const float* q) {
    int x = row * stride, sw = (row & 7) << 4;
    float d = 0.0f;
    #pragma unroll
    for (int c = 0; c < 4; ++c) {
        u16x8 t = *(const u16x8*)(base + ((x + cb + c * 16) ^ sw));
        #pragma unroll
        for (int j = 0; j < 8; ++j) d += q[c * 8 + j] * bf2f(t[j]);
    }
    return d;
}
// fused axpy: o[i] += a * lds_row[i] over 32 bf16 (8-elem transient)
__device__ __forceinline__ void lds_axpy32(const char* base, int stride, int row, int cb, float a, float* o) {
    int x = row * stride, sw = (row & 7) << 4;
    #pragma unroll
    for (int c = 0; c < 4; ++c) {
        u16x8 t = *(const u16x8*)(base + ((x + cb + c * 16) ^ sw));
        #pragma unroll
        for (int j = 0; j < 8; ++j) o[c * 8 + j] += a * bf2f(t[j]);
    }
}

// ---------------------------------------------------------------------------
// Two-pass LN over 256 cols, 128 rows (512 thr: row=tid>>2, quarter (tid&3)*64).
// Pass A accumulates sum/sumsq (live ~12 regs), pass B re-reads and normalizes.
// MODE 0: residual = [hi(aHi,stride256) | lo(aLo,stride256)]; MODE 2: none.
// OUT: write f32 global instead of xs.
// ---------------------------------------------------------------------------
template<int MODE, bool OUT>
__device__ __forceinline__ void ln_rows(char* xs, const char* aHi, const char* aLo,
                                        const float* g, const float* b, int tid,
                                        float* outp)
{
    int row = tid >> 2, c0 = (tid & 3) * 64;
    int x = row * 512, sw = (row & 7) << 4;
    const char* ab = (c0 < 128) ? aHi : aLo;
    int cb = ((c0 < 128) ? c0 : c0 - 128) * 2;
    int xr = row * 256;
    float s = 0.0f, sq = 0.0f;
    #pragma unroll
    for (int c = 0; c < 8; ++c) {
        u16x8 t = *(const u16x8*)(xs + ((x + c0 * 2 + c * 16) ^ sw));
        u16x8 r = {};
        if (MODE == 0) r = *(const u16x8*)(ab + ((xr + cb + c * 16) ^ sw));
        #pragma unroll
        for (int j = 0; j < 8; ++j) {
            float v = bf2f(t[j]) + ((MODE == 0) ? bf2f(r[j]) : 0.0f);
            s += v; sq += v * v;
        }
    }
    s += __shfl_xor(s, 1); s += __shfl_xor(s, 2);
    sq += __shfl_xor(sq, 1); sq += __shfl_xor(sq, 2);
    float mean = s * (1.0f / 256.0f);
    float var = sq * (1.0f / 256.0f) - mean * mean;
    float rstd = rsqrtf(var + 1e-5f);
    #pragma unroll
    for (int c = 0; c < 8; ++c) {
        u16x8 t = *(const u16x8*)(xs + ((x + c0 * 2 + c * 16) ^ sw));
        u16x8 r = {};
        if (MODE == 0) r = *(const u16x8*)(ab + ((xr + cb + c * 16) ^ sw));
        if (OUT) {
            float* op = outp + (size_t)row * 256 + c0 + c * 8;
            f32x4 o1, o2;
            #pragma unroll
            for (int j = 0; j < 4; ++j) {
                float v = bf2f(t[j]) + ((MODE == 0) ? bf2f(r[j]) : 0.0f);
                o1[j] = (v - mean) * rstd * g[c0 + c * 8 + j] + b[c0 + c * 8 + j];
            }
            #pragma unroll
            for (int j = 0; j < 4; ++j) {
                float v = bf2f(t[4 + j]) + ((MODE == 0) ? bf2f(r[4 + j]) : 0.0f);
                o2[j] = (v - mean) * rstd * g[c0 + c * 8 + 4 + j] + b[c0 + c * 8 + 4 + j];
            }
            *(f32x4*)op = o1;
            *(f32x4*)(op + 4) = o2;
        } else {
            u16x8 onew;
            #pragma unroll
            for (int j = 0; j < 8; ++j) {
                float v = bf2f(t[j]) + ((MODE == 0) ? bf2f(r[j]) : 0.0f);
                onew[j] = f2bf((v - mean) * rstd * g[c0 + c * 8 + j] + b[c0 + c * 8 + j]);
            }
            *(u16x8*)(xs + ((x + c0 * 2 + c * 16) ^ sw)) = onew;
        }
    }
}

// ---------------------------------------------------------------------------
// Two-pass LN over 256 cols for a 64-row half (512 thr: lrow=tid>>3, 32 cols).
// residual fs: 64 rows, stride 512, local-row swizzle. Writes xs (bf16).
// ---------------------------------------------------------------------------
__device__ __forceinline__ void ln_half(char* xs, const char* fs, int m0,
                                        const float* g, const float* b, int tid)
{
    int lrow = tid >> 3, c0 = (tid & 7) * 32;
    int row = m0 + lrow;
    int x = row * 512, sw = (row & 7) << 4;
    int xf = lrow * 512, swf = (lrow & 7) << 4;
    float s = 0.0f, sq = 0.0f;
    #pragma unroll
    for (int c = 0; c < 4; ++c) {
        u16x8 t = *(const u16x8*)(xs + ((x + c0 * 2 + c * 16) ^ sw));
        u16x8 f = *(const u16x8*)(fs + ((xf + c0 * 2 + c * 16) ^ swf));
        #pragma unroll
        for (int j = 0; j < 8; ++j) {
            float v = bf2f(t[j]) + bf2f(f[j]);
            s += v; sq += v * v;
        }
    }
    s += __shfl_xor(s, 1); s += __shfl_xor(s, 2); s += __shfl_xor(s, 4);
    sq += __shfl_xor(sq, 1); sq += __shfl_xor(sq, 2); sq += __shfl_xor(sq, 4);
    float mean = s * (1.0f / 256.0f);
    float var = sq * (1.0f / 256.0f) - mean * mean;
    float rstd = rsqrtf(var + 1e-5f);
    #pragma unroll
    for (int c = 0; c < 4; ++c) {
        u16x8 t = *(const u16x8*)(xs + ((x + c0 * 2 + c * 16) ^ sw));
        u16x8 f = *(const u16x8*)(fs + ((xf + c0 * 2 + c * 16) ^ swf));
        u16x8 onew;
        #pragma unroll
        for (int j = 0; j < 8; ++j) {
            float v = bf2f(t[j]) + bf2f(f[j]);
            onew[j] = f2bf((v - mean) * rstd * g[c0 + c * 8 + j] + b[c0 + c * 8 + j]);
        }
        *(u16x8*)(xs + ((x + c0 * 2 + c * 16) ^ sw)) = onew;
    }
}

// ---------------------------------------------------------------------------
// The mega-kernel. 512 threads = 8 waves (2m x 4n for 128-row GEMMs).
// Dynamic LDS 160 KiB: xs[128][256]bf16 (64K) | sbuf 96K = R0|R1|R2 (32K each).
// ---------------------------------------------------------------------------
__global__ __launch_bounds__(512)
__attribute__((amdgpu_waves_per_eu(2, 2)))
void enc_kernel(
    const float* __restrict__ tgt,
    const unsigned short* __restrict__ tWhqkv,  // [L][384][256]
    const unsigned short* __restrict__ tWhp,    // [L][128][128]
    const unsigned short* __restrict__ tWlq,    // [L][128][256]
    const unsigned short* __restrict__ tWlkv,   // [L][256][256]
    const unsigned short* __restrict__ tWlp,    // [L][128][128]
    const unsigned short* __restrict__ tW1,     // [L][512][256]
    const unsigned short* __restrict__ tW2,     // [L][256][512]
    const float* __restrict__ bhp, const float* __restrict__ blp,
    const float* __restrict__ b1, const float* __restrict__ b2,
    const float* __restrict__ ln1g, const float* __restrict__ ln1b,
    const float* __restrict__ ln2g, const float* __restrict__ ln2b,
    const float* __restrict__ lnfg, const float* __restrict__ lnfb,
    float* __restrict__ out)
{
    extern __shared__ char smem[];
    char* xs = smem;              // [128] rows x 512 B (256 bf16), swizzled
    char* sb = smem + 65536;      // 96 KB scratch
    char* R0 = sb;
    char* R1 = sb + 32768;
    char* R2 = sb + 65536;

    const int tid = threadIdx.x;
    const int bc = blockIdx.x;
    const int w = tid >> 6, l = tid & 63;
    const int lr = l & 15, lk = l >> 4;
    const int wm = w >> 2, wn = w & 3;   // 2 x 4 wave grid

    // ---- load x tile: 128 rows x 256 f32 -> bf16 swizzled LDS ----
    {
        int row = tid >> 2, c0 = (tid & 3) * 64;
        const float* src = tgt + ((size_t)bc * 128 + row) * 256 + c0;
        int x = row * 512, sw = (row & 7) << 4;
        #pragma unroll
        for (int c = 0; c < 8; ++c) {
            f32x4 a = *(const f32x4*)(src + c * 8);
            f32x4 bq = *(const f32x4*)(src + c * 8 + 4);
            u16x8 t;
            #pragma unroll
            for (int j = 0; j < 4; ++j) { t[j] = f2bf(a[j]); t[4 + j] = f2bf(bq[j]); }
            *(u16x8*)(xs + ((x + c0 * 2 + c * 16) ^ sw)) = t;
        }
    }
    __syncthreads();

    for (int li = 0; li < 2; ++li) {
        // ---- P1: qkv = xs @ WhqkvT (128x384, K=256), two 48-col passes ----
        #pragma unroll
        for (int p = 0; p < 2; ++p) {
            f32x4 acc[4][3] = {};
            mfma_gemm<4, 3, 8>(xs, 512, wm * 64,
                tWhqkv + (size_t)li * 98304 + (size_t)(wn * 96 + p * 48) * 256, 256, 0, lr, lk, acc);
            store_lds<4, 3, false>(sb, 768, wm * 64, wn * 96 + p * 48, nullptr, lr, lk, acc);
        }
        __syncthreads();
        // ---- P2: hifi windowed attention (thread = win,h,qi) ----
        {
            int win = tid >> 4, h = (tid >> 2) & 3, qi = tid & 3;
            int rbase = ((win >> 3) << 5) + ((win & 7) << 1);
            int qrow = rbase + ((qi >> 1) << 4) + (qi & 1);
            float q[32];
            lds_read32(sb, 768, qrow, h * 64, q);
            float s4[4];
            #pragma unroll
            for (int j = 0; j < 4; ++j) {
                int kr = rbase + ((j >> 1) << 4) + (j & 1);
                s4[j] = lds_dot32(sb, 768, kr, 256 + h * 64, q) * ATT_SCALE;
            }
            float mx = fmaxf(fmaxf(s4[0], s4[1]), fmaxf(s4[2], s4[3]));
            float den = 0.0f;
            #pragma unroll
            for (int j = 0; j < 4; ++j) { s4[j] = __expf(s4[j] - mx); den += s4[j]; }
            float inv = 1.0f / den;
            float o[32];
            #pragma unroll
            for (int i = 0; i < 32; ++i) o[i] = 0.0f;
            #pragma unroll
            for (int j = 0; j < 4; ++j) {
                int vr = rbase + ((j >> 1) << 4) + (j & 1);
                lds_axpy32(sb, 768, vr, 512 + h * 64, s4[j] * inv, o);
            }
            // qkv spans ALL of sb (128 rows x 768 B = 96 KB = R0|R1|R2);
            // writing os to R0 aliases qkv rows 0..42 -> MUST barrier first.
            __syncthreads();
            lds_write32(R0, 256, qrow, h * 64, o);  // os -> R0
        }
        __syncthreads();
        // ---- P3: hi = os @ WhpT + bhp -> R1 (as_hi) ----
        {
            f32x4 acc[4][2] = {};
            mfma_gemm<4, 2, 4>(R0, 256, wm * 64,
                tWhp + (size_t)li * 16384 + (size_t)(wn * 32) * 128, 128, 0, lr, lk, acc);
            store_lds<4, 2, false>(R1, 256, wm * 64, wn * 32,
                bhp + li * 128 + wn * 32, lr, lk, acc);
        }
        __syncthreads();
        // ---- P4: pool 2x2 windows -> xps R2[0:16K], [32][256] stride 512 ----
        {
            int p = tid >> 4, c16 = (tid & 15) * 16;
            int rb = ((p >> 3) << 5) + ((p & 7) << 1);
            int rows[4] = {rb, rb + 1, rb + 16, rb + 17};
            float a16[16] = {};
            #pragma unroll
            for (int rr = 0; rr < 4; ++rr) {
                int r = rows[rr];
                int x = r * 512, sw = (r & 7) << 4;
                #pragma unroll
                for (int c = 0; c < 2; ++c) {
                    u16x8 t = *(const u16x8*)(xs + ((x + c16 * 2 + c * 16) ^ sw));
                    #pragma unroll
                    for (int j = 0; j < 8; ++j) a16[c * 8 + j] += bf2f(t[j]);
                }
            }
            int x = p * 512, sw = (p & 7) << 4;
            #pragma unroll
            for (int c = 0; c < 2; ++c) {
                u16x8 t;
                #pragma unroll
                for (int j = 0; j < 8; ++j) t[j] = f2bf(a16[c * 8 + j] * 0.25f);
                *(u16x8*)(R2 + ((x + c16 * 2 + c * 16) ^ sw)) = t;
            }
        }
        __syncthreads();
        // ---- P5: kv = xps @ WlkvT (32x256) -> kvs R2+16K; P6: q = xs @ WlqT -> R0 ----
        {
            f32x4 acc[2][2] = {};
            mfma_gemm<2, 2, 8>(R2, 512, 0,
                tWlkv + (size_t)li * 65536 + (size_t)(w * 32) * 256, 256, 0, lr, lk, acc);
            store_lds<2, 2, false>(R2 + 16384, 512, 0, w * 32, nullptr, lr, lk, acc);
        }
        {
            f32x4 acc[4][2] = {};
            mfma_gemm<4, 2, 8>(xs, 512, wm * 64,
                tWlq + (size_t)li * 32768 + (size_t)(wn * 32) * 256, 256, 0, lr, lk, acc);
            store_lds<4, 2, false>(R0, 256, wm * 64, wn * 32, nullptr, lr, lk, acc);
        }
        __syncthreads();
        // ---- P7: lofi attention, two-pass softmax (thread = row,h) ----
        {
            int row = tid >> 2, h = tid & 3;
            float q[32];
            lds_read32(R0, 256, row, h * 64, q);
            // pass 1: row max (live: q + m)
            float m = -1e30f;
            #pragma unroll
            for (int p = 0; p < 32; ++p)
                m = fmaxf(m, lds_dot32(R2 + 16384, 512, p, h * 64, q));
            m *= ATT_SCALE;
            // pass 2: denominator + PV accumulate (live: q + o + den)
            float o[32];
            #pragma unroll
            for (int i = 0; i < 32; ++i) o[i] = 0.0f;
            float den = 0.0f;
            #pragma unroll
            for (int p = 0; p < 32; ++p) {
                float sv = lds_dot32(R2 + 16384, 512, p, h * 64, q) * ATT_SCALE;
                float pr = __expf(sv - m);
                den += pr;
                lds_axpy32(R2 + 16384, 512, p, 256 + h * 64, pr, o);
            }
            float inv = 1.0f / den;
            #pragma unroll
            for (int i = 0; i < 32; ++i) o[i] *= inv;
            // los rows >= 64 overlap the kvs region [16K:32K] -> barrier first.
            __syncthreads();
            lds_write32(R2, 256, row, h * 64, o);   // los -> R2 stride 256
        }
        __syncthreads();
        // ---- P8: lo = los @ WlpT + blp -> R0 (as_lo) ----
        {
            f32x4 acc[4][2] = {};
            mfma_gemm<4, 2, 4>(R2, 256, wm * 64,
                tWlp + (size_t)li * 16384 + (size_t)(wn * 32) * 128, 128, 0, lr, lk, acc);
            store_lds<4, 2, false>(R0, 256, wm * 64, wn * 32,
                blp + li * 128 + wn * 32, lr, lk, acc);
        }
        __syncthreads();
        // ---- P9: x = LN(x + [hi|lo]) ----
        ln_rows<0, false>(xs, R1, R0, ln1g + li * 256, ln1b + li * 256, tid, nullptr);
        __syncthreads();
        // ---- P10/P11/P12: FFN + LN2, two 64-row halves (peak acc = 64) ----
        #pragma unroll
        for (int half = 0; half < 2; ++half) {
            int m0 = half * 64;
            {   // hidden: 64 rows x 512 cols, each wave 64 cols. -> R0R1 stride 1024
                f32x4 acch[4][4] = {};
                mfma_gemm<4, 4, 8>(xs, 512, m0,
                    tW1 + (size_t)li * 131072 + (size_t)(w * 64) * 256, 256, 0, lr, lk, acch);
                store_lds<4, 4, true>(R0, 1024, 0, w * 64,
                    b1 + li * 512 + w * 64, lr, lk, acch);
            }
            __syncthreads();
            {   // f: 64 rows x 256 cols, K=512; waves 2m x 4n (32 rows x 64 cols) -> R2
                f32x4 facc[2][4] = {};
                mfma_gemm<2, 4, 16>(R0, 1024, (w >> 2) * 32,
                    tW2 + (size_t)li * 131072 + (size_t)((w & 3) * 64) * 512, 512, 0, lr, lk, facc);
                store_lds<2, 4, false>(R2, 512, (w >> 2) * 32, (w & 3) * 64,
                    b2 + li * 256 + (w & 3) * 64, lr, lk, facc);
            }
            __syncthreads();
            // x[m0:m0+64] = LN(x + f)
            ln_half(xs, R2, m0, ln2g + li * 256, ln2b + li * 256, tid);
            __syncthreads();
        }
    }
    // ---- final LN -> out (f32) ----
    ln_rows<2, true>(xs, nullptr, nullptr, lnfg, lnfb, tid, out + (size_t)bc * 32768);
}

// ---------------------------------------------------------------------------
extern "C" void kernel_launch(void* const* d_in, const int* in_sizes, int n_in,
                              void* d_out, int out_size, void* d_ws, size_t ws_size,
                              hipStream_t stream)
{
    (void)in_sizes; (void)n_in; (void)out_size; (void)ws_size;
    const float* tgt   = (const float*)d_in[0];
    const float* Wlq   = (const float*)d_in[1];
    const float* Wlkv  = (const float*)d_in[2];
    const float* Wlp   = (const float*)d_in[3];
    const float* blp   = (const float*)d_in[4];
    const float* Whqkv = (const float*)d_in[5];
    const float* Whp   = (const float*)d_in[6];
    const float* bhp   = (const float*)d_in[7];
    const float* W1    = (const float*)d_in[8];
    const float* b1    = (const float*)d_in[9];
    const float* W2    = (const float*)d_in[10];
    const float* b2    = (const float*)d_in[11];
    const float* ln1g  = (const float*)d_in[12];
    const float* ln1b  = (const float*)d_in[13];
    const float* ln2g  = (const float*)d_in[14];
    const float* ln2b  = (const float*)d_in[15];
    const float* lnfg  = (const float*)d_in[16];
    const float* lnfb  = (const float*)d_in[17];

    unsigned short* wsu = (unsigned short*)d_ws;
    unsigned short* tWhqkv = wsu;             // 2*384*256 = 196608
    unsigned short* tWhp   = wsu + 196608;    // 2*128*128 =  32768
    unsigned short* tWlq   = wsu + 229376;    // 2*128*256 =  65536
    unsigned short* tWlkv  = wsu + 294912;    // 2*256*256 = 131072
    unsigned short* tWlp   = wsu + 425984;    // 2*128*128 =  32768
    unsigned short* tW1    = wsu + 458752;    // 2*512*256 = 262144
    unsigned short* tW2    = wsu + 720896;    // 2*256*512 = 262144

    wprep<<<dim3(8, 12, 2), 256, 0, stream>>>(Whqkv, tWhqkv, 256, 384);
    wprep<<<dim3(4,  4, 2), 256, 0, stream>>>(Whp,   tWhp,   128, 128);
    wprep<<<dim3(8,  4, 2), 256, 0, stream>>>(Wlq,   tWlq,   256, 128);
    wprep<<<dim3(8,  8, 2), 256, 0, stream>>>(Wlkv,  tWlkv,  256, 256);
    wprep<<<dim3(4,  4, 2), 256, 0, stream>>>(Wlp,   tWlp,   128, 128);
    wprep<<<dim3(8, 16, 2), 256, 0, stream>>>(W1,    tW1,    256, 512);
    wprep<<<dim3(16, 8, 2), 256, 0, stream>>>(W2,    tW2,    512, 256);

    hipFuncSetAttribute((const void*)enc_kernel,
                        hipFuncAttributeMaxDynamicSharedMemorySize, 163840);
    enc_kernel<<<1024, 512, 163840, stream>>>(
        tgt, tWhqkv, tWhp, tWlq, tWlkv, tWlp, tW1, tW2,
        bhp, blp, b1, b2, ln1g, ln1b, ln2g, ln2b, lnfg, lnfb, (float*)d_out);
}

// Round 7
// 1050.796 us; speedup vs baseline: 4.8235x; 4.8235x over previous
//
#include <hip/hip_runtime.h>
#include <hip/hip_bf16.h>

// ---------------------------------------------------------------------------
// WinEncoderTransformer, multi-kernel pipeline, bf16 activations end-to-end.
// R6: abandoned the mega-kernel (compiler pins it at 128 VGPR -> per-thread
// arrays spill -> 3-9 GB scratch traffic dominated). Back to the R1 pipeline
// structure (known-good) with: bf16 activations (halves all streams), bf16
// pre-transposed weights (16B staging loads), fused residual+LN kernels, and
// a fused LN2+LNfinal tail (f32 precision, saves one full pass).
// Geometry: N=128, B=1024, C=256; R = 131072 rows. Row r: bc=r>>7, win row
// mapping rbase = bc*128 + (tw>>3)*32 + (tw&7)*2 (verified in R1).
// ---------------------------------------------------------------------------

#define RT 131072ull
#define ATT_SCALE 0.17677669529663687f   // 32^-0.5

typedef float f32x4 __attribute__((ext_vector_type(4)));
typedef __bf16 bf16x8 __attribute__((ext_vector_type(8)));
typedef unsigned short u16x8 __attribute__((ext_vector_type(8)));
typedef unsigned short u16x4 __attribute__((ext_vector_type(4)));

__device__ __forceinline__ unsigned short f2bf(float f) {
    unsigned int u = __float_as_uint(f);
    return (unsigned short)((u + 0x7FFFu + ((u >> 16) & 1u)) >> 16);  // RNE
}
__device__ __forceinline__ float bf2f(unsigned short s) {
    return __uint_as_float(((unsigned int)s) << 16);
}

// ---------------------------------------------------------------------------
// weight prep: src [L][K][N] f32 -> dst [L][N][K] bf16 (transposed)
// ---------------------------------------------------------------------------
__global__ __launch_bounds__(256) void wprep(const float* __restrict__ src,
                                             unsigned short* __restrict__ dst,
                                             int K, int N)
{
    __shared__ unsigned short t[32][33];
    int l = blockIdx.z;
    const float* s = src + (size_t)l * K * N;
    unsigned short* d = dst + (size_t)l * K * N;
    int r = threadIdx.x >> 3, c4 = (threadIdx.x & 7) * 4;
    int kb = blockIdx.x * 32, nb = blockIdx.y * 32;
    f32x4 v = *(const f32x4*)(s + (size_t)(kb + r) * N + nb + c4);
    #pragma unroll
    for (int j = 0; j < 4; ++j) t[c4 + j][r] = f2bf(v[j]);
    __syncthreads();
    u16x4 o;
    #pragma unroll
    for (int j = 0; j < 4; ++j) o[j] = t[r][c4 + j];
    *(u16x4*)(d + (size_t)(nb + r) * K + kb + c4) = o;
}

// ---------------------------------------------------------------------------
// cvt: tgt f32 -> x bf16
// ---------------------------------------------------------------------------
__global__ __launch_bounds__(256) void cvt_bf16(const float* __restrict__ src,
                                                unsigned short* __restrict__ dst)
{
    size_t i = ((size_t)blockIdx.x * 256 + threadIdx.x) * 8;
    f32x4 a = *(const f32x4*)(src + i);
    f32x4 b = *(const f32x4*)(src + i + 4);
    u16x8 t;
    #pragma unroll
    for (int j = 0; j < 4; ++j) { t[j] = f2bf(a[j]); t[4 + j] = f2bf(b[j]); }
    *(u16x8*)(dst + i) = t;
}

// ---------------------------------------------------------------------------
// GEMM: C[M x N] = A[M x K] @ BT[N x K]^T (+bias)(+relu), bf16 in/out, MFMA.
// BM=128, BN=64, BK=64, 256 threads (2x2 waves). XOR-swizzled LDS.
// ---------------------------------------------------------------------------
template<bool BIAS, bool RELU>
__global__ __launch_bounds__(256) void gemm_bb(
    const unsigned short* __restrict__ A, int lda,
    const unsigned short* __restrict__ BT,
    const float* __restrict__ bias,
    unsigned short* __restrict__ C, int ldc, int K)
{
    __shared__ __align__(16) char As[128 * 128];  // 128 rows x 128B (64 bf16)
    __shared__ __align__(16) char Bs[64 * 128];   // 64 rows x 128B

    const int tid = threadIdx.x;
    const size_t m0 = (size_t)blockIdx.x * 128;
    const int n0 = blockIdx.y * 64;
    const int w = tid >> 6, l = tid & 63;
    const int lr = l & 15, lk = l >> 4;
    const int wm = w >> 1, wn = w & 1;

    f32x4 acc[4][2] = {};

    for (int k0 = 0; k0 < K; k0 += 64) {
        #pragma unroll
        for (int i = 0; i < 4; ++i) {
            int cid = tid + i * 256, row = cid >> 3, kc = cid & 7;
            u16x8 t = *(const u16x8*)(A + (m0 + row) * lda + k0 + kc * 8);
            *(u16x8*)(As + ((row * 128 + kc * 16) ^ ((row & 7) << 4))) = t;
        }
        #pragma unroll
        for (int i = 0; i < 2; ++i) {
            int fid = tid + i * 256, row = fid >> 3, kc = fid & 7;
            u16x8 t = *(const u16x8*)(BT + (size_t)(n0 + row) * K + k0 + kc * 8);
            *(u16x8*)(Bs + ((row * 128 + kc * 16) ^ ((row & 7) << 4))) = t;
        }
        __syncthreads();
        #pragma unroll
        for (int s = 0; s < 2; ++s) {
            bf16x8 bfr[2];
            #pragma unroll
            for (int nt = 0; nt < 2; ++nt) {
                int r = wn * 32 + nt * 16 + lr;
                bfr[nt] = *(const bf16x8*)(Bs + ((r * 128 + s * 64 + lk * 16) ^ ((r & 7) << 4)));
            }
            #pragma unroll
            for (int mt = 0; mt < 4; ++mt) {
                int r = wm * 64 + mt * 16 + lr;
                bf16x8 afr = *(const bf16x8*)(As + ((r * 128 + s * 64 + lk * 16) ^ ((r & 7) << 4)));
                acc[mt][0] = __builtin_amdgcn_mfma_f32_16x16x32_bf16(afr, bfr[0], acc[mt][0], 0, 0, 0);
                acc[mt][1] = __builtin_amdgcn_mfma_f32_16x16x32_bf16(afr, bfr[1], acc[mt][1], 0, 0, 0);
            }
        }
        __syncthreads();
    }
    // epilogue: C/D layout col=lane&15, row=(lane>>4)*4+j (m89-verified)
    #pragma unroll
    for (int nt = 0; nt < 2; ++nt) {
        int col = n0 + wn * 32 + nt * 16 + lr;
        float bv = BIAS ? bias[col] : 0.0f;
        #pragma unroll
        for (int mt = 0; mt < 4; ++mt) {
            #pragma unroll
            for (int j = 0; j < 4; ++j) {
                size_t row = m0 + (size_t)(wm * 64 + mt * 16 + lk * 4 + j);
                float v = acc[mt][nt][j] + bv;
                if (RELU) v = fmaxf(v, 0.0f);
                C[row * ldc + col] = f2bf(v);
            }
        }
    }
}

// ---------------------------------------------------------------------------
// hifi: windowed 4-token attention, bf16 qkv [R][384] = [q 4h*32 | k | v].
// One thread per (window, head, query).
// ---------------------------------------------------------------------------
__global__ __launch_bounds__(256) void hifi_attn(const unsigned short* __restrict__ qkv,
                                                 unsigned short* __restrict__ os)
{
    int t = blockIdx.x * 256 + threadIdx.x;
    int wdw = t >> 4, h = (t >> 2) & 3, qi = t & 3;
    int bc = wdw >> 5, tw = wdw & 31;
    int rbase = bc * 128 + (tw >> 3) * 32 + (tw & 7) * 2;
    int qrow = rbase + ((qi >> 1) << 4) + (qi & 1);

    const unsigned short* qp = qkv + (size_t)qrow * 384 + h * 32;
    float q[32];
    #pragma unroll
    for (int c = 0; c < 4; ++c) {
        u16x8 v = *(const u16x8*)(qp + c * 8);
        #pragma unroll
        for (int j = 0; j < 8; ++j) q[c * 8 + j] = bf2f(v[j]);
    }
    float s4[4];
    #pragma unroll
    for (int j = 0; j < 4; ++j) {
        int kr = rbase + ((j >> 1) << 4) + (j & 1);
        const unsigned short* kp = qkv + (size_t)kr * 384 + 128 + h * 32;
        float d = 0.0f;
        #pragma unroll
        for (int c = 0; c < 4; ++c) {
            u16x8 v = *(const u16x8*)(kp + c * 8);
            #pragma unroll
            for (int jj = 0; jj < 8; ++jj) d += q[c * 8 + jj] * bf2f(v[jj]);
        }
        s4[j] = d * ATT_SCALE;
    }
    float mx = fmaxf(fmaxf(s4[0], s4[1]), fmaxf(s4[2], s4[3]));
    float den = 0.0f;
    #pragma unroll
    for (int j = 0; j < 4; ++j) { s4[j] = __expf(s4[j] - mx); den += s4[j]; }
    float inv = 1.0f / den;

    float o[32];
    #pragma unroll
    for (int i = 0; i < 32; ++i) o[i] = 0.0f;
    #pragma unroll
    for (int j = 0; j < 4; ++j) {
        int vr = rbase + ((j >> 1) << 4) + (j & 1);
        const unsigned short* vp = qkv + (size_t)vr * 384 + 256 + h * 32;
        float a = s4[j] * inv;
        #pragma unroll
        for (int c = 0; c < 4; ++c) {
            u16x8 v = *(const u16x8*)(vp + c * 8);
            #pragma unroll
            for (int jj = 0; jj < 8; ++jj) o[c * 8 + jj] += a * bf2f(v[jj]);
        }
    }
    unsigned short* op = os + (size_t)qrow * 128 + h * 32;
    #pragma unroll
    for (int c = 0; c < 4; ++c) {
        u16x8 v;
        #pragma unroll
        for (int j = 0; j < 8; ++j) v[j] = f2bf(o[c * 8 + j]);
        *(u16x8*)(op + c * 8) = v;
    }
}

// ---------------------------------------------------------------------------
// pool: xp[p][c] = mean of the 2x2 window's 4 rows (bf16 in/out)
// ---------------------------------------------------------------------------
__global__ __launch_bounds__(256) void pool_k(const unsigned short* __restrict__ x,
                                              unsigned short* __restrict__ xp)
{
    int id = blockIdx.x * 256 + threadIdx.x;   // p*32 + chunk8
    int p = id >> 5, c8 = (id & 31) * 8;
    int bc = p >> 5, tw = p & 31;
    int rbase = bc * 128 + (tw >> 3) * 32 + (tw & 7) * 2;
    const unsigned short* x0 = x + (size_t)rbase * 256 + c8;
    float a[8] = {};
    const int offs[4] = {0, 256, 16 * 256, 17 * 256};
    #pragma unroll
    for (int r = 0; r < 4; ++r) {
        u16x8 v = *(const u16x8*)(x0 + offs[r]);
        #pragma unroll
        for (int j = 0; j < 8; ++j) a[j] += bf2f(v[j]);
    }
    u16x8 o;
    #pragma unroll
    for (int j = 0; j < 8; ++j) o[j] = f2bf(a[j] * 0.25f);
    *(u16x8*)(xp + (size_t)p * 256 + c8) = o;
}

// ---------------------------------------------------------------------------
// lofi: 128 queries vs 32 pooled kv per (bc, head). Block = 128 threads;
// k/v staged to padded LDS (broadcast reads). kv row = [k 4h*32 | v 4h*32].
// ---------------------------------------------------------------------------
__global__ __launch_bounds__(128) void lofi_attn(const unsigned short* __restrict__ qb,
                                                 const unsigned short* __restrict__ kvb,
                                                 unsigned short* __restrict__ ob)
{
    __shared__ float ks[32][36];
    __shared__ float vs[32][36];
    int bc = blockIdx.x >> 2, h = blockIdx.x & 3;
    int tid = threadIdx.x;

    #pragma unroll
    for (int i = 0; i < 2; ++i) {
        int fid = tid + i * 128;              // 256 chunks of 4
        int row = fid >> 3, cc = (fid & 7) * 4;
        const unsigned short* kp = kvb + (size_t)(bc * 32 + row) * 256 + h * 32 + cc;
        u16x4 kk = *(const u16x4*)kp;
        u16x4 vv = *(const u16x4*)(kp + 128);
        #pragma unroll
        for (int j = 0; j < 4; ++j) { ks[row][cc + j] = bf2f(kk[j]); vs[row][cc + j] = bf2f(vv[j]); }
    }

    const unsigned short* qp = qb + (size_t)(bc * 128 + tid) * 128 + h * 32;
    float q[32];
    #pragma unroll
    for (int c = 0; c < 4; ++c) {
        u16x8 v = *(const u16x8*)(qp + c * 8);
        #pragma unroll
        for (int j = 0; j < 8; ++j) q[c * 8 + j] = bf2f(v[j]);
    }
    __syncthreads();

    float sc[32];
    #pragma unroll
    for (int tk = 0; tk < 32; ++tk) {
        float d = 0.0f;
        #pragma unroll
        for (int i = 0; i < 32; ++i) d += q[i] * ks[tk][i];
        sc[tk] = d * ATT_SCALE;
    }
    float mx = -1e30f;
    #pragma unroll
    for (int tk = 0; tk < 32; ++tk) mx = fmaxf(mx, sc[tk]);
    float den = 0.0f;
    #pragma unroll
    for (int tk = 0; tk < 32; ++tk) { sc[tk] = __expf(sc[tk] - mx); den += sc[tk]; }
    float inv = 1.0f / den;

    float o[32];
    #pragma unroll
    for (int i = 0; i < 32; ++i) o[i] = 0.0f;
    #pragma unroll
    for (int tk = 0; tk < 32; ++tk) {
        float a = sc[tk];
        #pragma unroll
        for (int i = 0; i < 32; ++i) o[i] += a * vs[tk][i];
    }
    unsigned short* op = ob + (size_t)(bc * 128 + tid) * 128 + h * 32;
    #pragma unroll
    for (int c = 0; c < 4; ++c) {
        u16x8 v;
        #pragma unroll
        for (int j = 0; j < 8; ++j) v[j] = f2bf(o[c * 8 + j] * inv);
        *(u16x8*)(op + c * 8) = v;
    }
}

// ---------------------------------------------------------------------------
// addln: one 64-lane wave per row (4 rows/block), lane holds 4 cols.
// MODE 0: x + [hi|lo] -> LN -> x bf16
// MODE 1: x + f       -> LN -> x bf16
// MODE 2: x + f -> LN2 -> LNf -> out f32 (fused tail, f32 precision)
// ---------------------------------------------------------------------------
template<int MODE>
__global__ __launch_bounds__(256) void addln(
    const unsigned short* __restrict__ x,
    const unsigned short* __restrict__ r1,
    const unsigned short* __restrict__ r2,
    const float* __restrict__ g, const float* __restrict__ b,
    const float* __restrict__ g2, const float* __restrict__ b2,
    unsigned short* __restrict__ xout, float* __restrict__ fout)
{
    size_t row = (size_t)blockIdx.x * 4 + (threadIdx.x >> 6);
    int l = threadIdx.x & 63;
    u16x4 xv = *(const u16x4*)(x + row * 256 + l * 4);
    f32x4 v;
    #pragma unroll
    for (int j = 0; j < 4; ++j) v[j] = bf2f(xv[j]);
    if (MODE == 0) {
        const unsigned short* rp = (l < 32) ? (r1 + row * 128 + l * 4)
                                            : (r2 + row * 128 + (l - 32) * 4);
        u16x4 rv = *(const u16x4*)rp;
        #pragma unroll
        for (int j = 0; j < 4; ++j) v[j] += bf2f(rv[j]);
    } else {
        u16x4 rv = *(const u16x4*)(r1 + row * 256 + l * 4);
        #pragma unroll
        for (int j = 0; j < 4; ++j) v[j] += bf2f(rv[j]);
    }
    float s = v[0] + v[1] + v[2] + v[3];
    float sq = v[0] * v[0] + v[1] * v[1] + v[2] * v[2] + v[3] * v[3];
    #pragma unroll
    for (int off = 32; off > 0; off >>= 1) { s += __shfl_xor(s, off); sq += __shfl_xor(sq, off); }
    float mean = s * (1.0f / 256.0f);
    float var = sq * (1.0f / 256.0f) - mean * mean;
    float rstd = rsqrtf(var + 1e-5f);
    f32x4 gv = *(const f32x4*)(g + l * 4);
    f32x4 bv = *(const f32x4*)(b + l * 4);
    f32x4 o;
    #pragma unroll
    for (int j = 0; j < 4; ++j) o[j] = (v[j] - mean) * rstd * gv[j] + bv[j];
    if (MODE == 2) {
        float s2 = o[0] + o[1] + o[2] + o[3];
        float sq2 = o[0] * o[0] + o[1] * o[1] + o[2] * o[2] + o[3] * o[3];
        #pragma unroll
        for (int off = 32; off > 0; off >>= 1) { s2 += __shfl_xor(s2, off); sq2 += __shfl_xor(sq2, off); }
        float mean2 = s2 * (1.0f / 256.0f);
        float var2 = sq2 * (1.0f / 256.0f) - mean2 * mean2;
        float rstd2 = rsqrtf(var2 + 1e-5f);
        f32x4 g2v = *(const f32x4*)(g2 + l * 4);
        f32x4 b2v = *(const f32x4*)(b2 + l * 4);
        f32x4 f;
        #pragma unroll
        for (int j = 0; j < 4; ++j) f[j] = (o[j] - mean2) * rstd2 * g2v[j] + b2v[j];
        *(f32x4*)(fout + row * 256 + l * 4) = f;
    } else {
        u16x4 t;
        #pragma unroll
        for (int j = 0; j < 4; ++j) t[j] = f2bf(o[j]);
        *(u16x4*)(xout + row * 256 + l * 4) = t;
    }
}

// ---------------------------------------------------------------------------
extern "C" void kernel_launch(void* const* d_in, const int* in_sizes, int n_in,
                              void* d_out, int out_size, void* d_ws, size_t ws_size,
                              hipStream_t stream)
{
    (void)in_sizes; (void)n_in; (void)out_size; (void)ws_size;
    const float* tgt   = (const float*)d_in[0];
    const float* Wlq   = (const float*)d_in[1];
    const float* Wlkv  = (const float*)d_in[2];
    const float* Wlp   = (const float*)d_in[3];
    const float* blp   = (const float*)d_in[4];
    const float* Whqkv = (const float*)d_in[5];
    const float* Whp   = (const float*)d_in[6];
    const float* bhp   = (const float*)d_in[7];
    const float* W1    = (const float*)d_in[8];
    const float* b1    = (const float*)d_in[9];
    const float* W2    = (const float*)d_in[10];
    const float* b2    = (const float*)d_in[11];
    const float* ln1g  = (const float*)d_in[12];
    const float* ln1b  = (const float*)d_in[13];
    const float* ln2g  = (const float*)d_in[14];
    const float* ln2b  = (const float*)d_in[15];
    const float* lnfg  = (const float*)d_in[16];
    const float* lnfb  = (const float*)d_in[17];

    unsigned short* wsu = (unsigned short*)d_ws;
    // transposed bf16 weights (983040 ushorts total)
    unsigned short* tWhqkv = wsu;             // 2*384*256
    unsigned short* tWhp   = wsu + 196608;    // 2*128*128
    unsigned short* tWlq   = wsu + 229376;    // 2*128*256
    unsigned short* tWlkv  = wsu + 294912;    // 2*256*256
    unsigned short* tWlp   = wsu + 425984;    // 2*128*128
    unsigned short* tW1    = wsu + 458752;    // 2*512*256
    unsigned short* tW2    = wsu + 720896;    // 2*256*512
    // activations (bf16), lifetime-overlapped (total ~371 MB):
    unsigned short* x    = wsu + 983040;                 // R*256
    unsigned short* qkv  = x + RT * 256;                 // R*384; f = qkv[0:R*256], los = qkv+R*256
    unsigned short* f    = qkv;
    unsigned short* los  = qkv + RT * 256;
    unsigned short* os   = qkv + RT * 384;               // R*128; qb reuses os
    unsigned short* qb   = os;
    unsigned short* xp   = os + RT * 128;                // 32768*256
    unsigned short* kv   = xp + 32768ull * 256;          // 32768*256
    unsigned short* hi   = kv + 32768ull * 256;          // R*128
    unsigned short* lo   = hi + RT * 128;                // R*128
    unsigned short* hbuf = hi;                           // R*512 (reuses hi+lo after addln1)

    wprep<<<dim3(8, 12, 2), 256, 0, stream>>>(Whqkv, tWhqkv, 256, 384);
    wprep<<<dim3(4,  4, 2), 256, 0, stream>>>(Whp,   tWhp,   128, 128);
    wprep<<<dim3(8,  4, 2), 256, 0, stream>>>(Wlq,   tWlq,   256, 128);
    wprep<<<dim3(8,  8, 2), 256, 0, stream>>>(Wlkv,  tWlkv,  256, 256);
    wprep<<<dim3(4,  4, 2), 256, 0, stream>>>(Wlp,   tWlp,   128, 128);
    wprep<<<dim3(8, 16, 2), 256, 0, stream>>>(W1,    tW1,    256, 512);
    wprep<<<dim3(16, 8, 2), 256, 0, stream>>>(W2,    tW2,    512, 256);

    cvt_bf16<<<16384, 256, 0, stream>>>(tgt, x);

    for (int li = 0; li < 2; ++li) {
        // 1. qkv = x @ WhqkvT
        gemm_bb<false, false><<<dim3(1024, 6), 256, 0, stream>>>(
            x, 256, tWhqkv + (size_t)li * 98304, nullptr, qkv, 384, 256);
        // 2. hifi window attention -> os
        hifi_attn<<<2048, 256, 0, stream>>>(qkv, os);
        // 3. hi = os @ WhpT + bhp
        gemm_bb<true, false><<<dim3(1024, 2), 256, 0, stream>>>(
            os, 128, tWhp + (size_t)li * 16384, bhp + li * 128, hi, 128, 128);
        // 4. qb = x @ WlqT   (qb aliases os — os dead after step 3)
        gemm_bb<false, false><<<dim3(1024, 2), 256, 0, stream>>>(
            x, 256, tWlq + (size_t)li * 32768, nullptr, qb, 128, 256);
        // 5. pool
        pool_k<<<4096, 256, 0, stream>>>(x, xp);
        // 6. kv = xp @ WlkvT   (M = 32768)
        gemm_bb<false, false><<<dim3(256, 4), 256, 0, stream>>>(
            xp, 256, tWlkv + (size_t)li * 65536, nullptr, kv, 256, 256);
        // 7. lofi attention -> los (aliases qkv tail — qkv dead after step 2)
        lofi_attn<<<4096, 128, 0, stream>>>(qb, kv, los);
        // 8. lo = los @ WlpT + blp
        gemm_bb<true, false><<<dim3(1024, 2), 256, 0, stream>>>(
            los, 128, tWlp + (size_t)li * 16384, blp + li * 128, lo, 128, 128);
        // 9. x = LN(x + [hi|lo])
        addln<0><<<32768, 256, 0, stream>>>(x, hi, lo, ln1g + li * 256, ln1b + li * 256,
                                            nullptr, nullptr, x, nullptr);
        // 10. h = relu(x @ W1T + b1)   (hbuf reuses hi/lo — dead after step 9)
        gemm_bb<true, true><<<dim3(1024, 8), 256, 0, stream>>>(
            x, 256, tW1 + (size_t)li * 131072, b1 + li * 512, hbuf, 512, 256);
        // 11. f = h @ W2T + b2   (f aliases qkv[0:R*256])
        gemm_bb<true, false><<<dim3(1024, 4), 256, 0, stream>>>(
            hbuf, 512, tW2 + (size_t)li * 131072, b2 + li * 256, f, 256, 512);
        // 12. x = LN(x + f)  |  layer 1: fused LN2 + final LN -> f32 out
        if (li == 0) {
            addln<1><<<32768, 256, 0, stream>>>(x, f, nullptr, ln2g, ln2b,
                                                nullptr, nullptr, x, nullptr);
        } else {
            addln<2><<<32768, 256, 0, stream>>>(x, f, nullptr, ln2g + 256, ln2b + 256,
                                                lnfg, lnfb, nullptr, (float*)d_out);
        }
    }
}